// Round 6
// baseline (194.006 us; speedup 1.0000x reference)
//

#include <hip/hip_runtime.h>
#include <hip/hip_bf16.h>
#include <math.h>

// ArcFace forward: out = S * modified, where modified == logits except at
// (row, label): cos(arccos(t) + MARGIN) = t*cos(m) - sqrt(1-t^2)*sin(m).
//
// R5 post-mortem: three structurally different kernels (guarded grid-stride,
// flat-8, pipelined-20) all pin at 61.5us / 2.5 TB/s; NT stores and ILP depth
// change NOTHING. Waves are queue-stalled => memory-path policy, not
// wave-side parallelism. Hypothesis: write-allocate churns the L3-resident
// input mid-kernel (FETCH=50MB = half evicted before read).
// R6 experiment: split the 3125 chunks mod 3 across three serialized
// dispatches differing ONLY in cache policy:
//   mode 0 = plain load / plain store   (control)
//   mode 1 = NT load    / plain store
//   mode 2 = NT load    / NT store
// Per-dispatch rocprof rows = 3 measurements in one bench.

#define ARC_S      64.0f
#define COS_M      0.8775825618903728f   // cos(0.5)
#define SIN_M      0.4794255386042030f   // sin(0.5)

typedef float floatx4 __attribute__((ext_vector_type(4)));

#define T_PER_BLK   256
#define F4_PER_THR  8
#define F4_PER_CHUNK (T_PER_BLK * F4_PER_THR)   // 2048 float4 = 32 KB

template<int MODE>
__global__ __launch_bounds__(256) void bulk_kernel(
    const floatx4* __restrict__ in,
    floatx4*       __restrict__ out,
    int parity)
{
    const size_t chunk = (size_t)blockIdx.x * 3 + (size_t)parity;
    const size_t base  = chunk * F4_PER_CHUNK + threadIdx.x;

    #pragma unroll
    for (int j = 0; j < F4_PER_THR; ++j) {
        const size_t idx = base + (size_t)j * T_PER_BLK;
        floatx4 v;
        if (MODE >= 1) v = __builtin_nontemporal_load(&in[idx]);
        else           v = in[idx];
        v *= ARC_S;
        if (MODE == 2) __builtin_nontemporal_store(v, &out[idx]);
        else           out[idx] = v;
    }
}

// (1) 256 target-element fixups, (2) any flat tail beyond full chunks
// (empty for 256x100000).
__global__ __launch_bounds__(256) void fixup_kernel(
    const float* __restrict__ logits,
    const int*   __restrict__ labels,
    float*       __restrict__ out,
    int B, int C, size_t tailStart, size_t total)
{
    const int t = threadIdx.x;

    if (t < B) {
        const int lbl = labels[t];
        if (lbl >= 0 && lbl < C) {
            const size_t idx = (size_t)t * (size_t)C + (size_t)lbl;
            const float x = logits[idx];
            const float s = sqrtf(fmaxf(0.0f, 1.0f - x * x));
            out[idx] = ARC_S * (x * COS_M - s * SIN_M);
        }
    }

    for (size_t i = tailStart + t; i < total; i += 256)
        out[i] = ARC_S * logits[i];
}

extern "C" void kernel_launch(void* const* d_in, const int* in_sizes, int n_in,
                              void* d_out, int out_size, void* d_ws, size_t ws_size,
                              hipStream_t stream) {
    const float* logits = (const float*)d_in[0];
    const int*   labels = (const int*)d_in[1];
    float*       out    = (float*)d_out;

    const int B = in_sizes[1];                 // 256
    const int C = in_sizes[0] / B;             // 100000
    const size_t total   = (size_t)B * (size_t)C;         // 25.6e6 floats
    const size_t total4  = total / 4;                     // 6.4e6 float4s
    const size_t nChunks = total4 / F4_PER_CHUNK;         // 3125
    const size_t tailStart = nChunks * F4_PER_CHUNK * 4u; // == total here

    // chunk ids mod 3: counts for parity 0/1/2
    const int n0 = (int)((nChunks + 2) / 3);   // 1042
    const int n1 = (int)((nChunks + 1) / 3);   // 1042
    const int n2 = (int)(nChunks / 3);         // 1041

    const floatx4* in4  = (const floatx4*)logits;
    floatx4*       out4 = (floatx4*)out;

    if (n0) bulk_kernel<0><<<dim3(n0), dim3(T_PER_BLK), 0, stream>>>(in4, out4, 0);
    if (n1) bulk_kernel<1><<<dim3(n1), dim3(T_PER_BLK), 0, stream>>>(in4, out4, 1);
    if (n2) bulk_kernel<2><<<dim3(n2), dim3(T_PER_BLK), 0, stream>>>(in4, out4, 2);

    fixup_kernel<<<dim3(1), dim3(256), 0, stream>>>(
        logits, labels, out, B, C, tailStart, total);
}
